// Round 14
// baseline (240.435 us; speedup 1.0000x reference)
//
#include <hip/hip_runtime.h>

typedef unsigned short ushort_t;
typedef __bf16 bf16x8 __attribute__((ext_vector_type(8)));
typedef float f32x4 __attribute__((ext_vector_type(4)));
typedef void __attribute__((address_space(1))) gvoid_t;
typedef void __attribute__((address_space(3))) lvoid_t;

__device__ __forceinline__ float bflo(unsigned u) { return __builtin_bit_cast(float, u << 16); }
__device__ __forceinline__ float bfhi(unsigned u) { return __builtin_bit_cast(float, u & 0xffff0000u); }
__device__ __forceinline__ unsigned f2bf_bits(float f) {
  unsigned u = __builtin_bit_cast(unsigned, f);
  return (u + 0x7fffu + ((u >> 16) & 1u)) >> 16;
}
__device__ __forceinline__ ushort_t f2bf(float f) { return (ushort_t)f2bf_bits(f); }

// ---------------- fused prep: x-transpose + w-pack + stats/flags zero ----------------
// blocks 0..1023:  x (b,c,h,w) f32 -> xt[b][h][w][c] bf16
// blocks 1024..1279: w (o,c,k) f32 -> wb[k][o][c] bf16;
//   block 1024 zeroes stats (256 f32), block 1025 zeroes flags (256 i32).
__global__ __launch_bounds__(256) void k_prep(const float* __restrict__ x,
                                              const float* __restrict__ w,
                                              ushort_t* __restrict__ xt,
                                              ushort_t* __restrict__ wb,
                                              float* __restrict__ stats,
                                              int* __restrict__ flags) {
  const int gid = blockIdx.x;  // 1280
  const int t = threadIdx.x;
  if (gid >= 1024) {
    if (gid == 1024) stats[t] = 0.f;
    if (gid == 1025) flags[t] = 0;
    const int idx = (gid - 1024) * 256 + t;  // (o,c) pair
    const float* src = w + (size_t)idx * 9;
    #pragma unroll
    for (int k = 0; k < 9; ++k)
      wb[(k << 16) + idx] = f2bf(src[k]);
    return;
  }
  __shared__ ushort_t tile[64][68];
  const int b = gid >> 8;
  const int ct = (gid >> 6) & 3;
  const int pt = gid & 63;
  const float* xb = x + ((size_t)(b * 256 + ct * 64)) * 4096 + pt * 64;
  #pragma unroll
  for (int i = 0; i < 16; ++i) {
    const int idx = t + 256 * i;
    const int c_l = idx >> 6, p_l = idx & 63;
    tile[c_l][p_l] = f2bf(xb[(size_t)c_l * 4096 + p_l]);
  }
  __syncthreads();
  ushort_t* xo = xt + ((size_t)(b * 4096 + pt * 64)) * 256 + ct * 64;
  #pragma unroll
  for (int i = 0; i < 16; ++i) {
    const int idx = t + 256 * i;
    const int p_l = idx >> 6, c_l = idx & 63;
    xo[(size_t)p_l * 256 + c_l] = tile[c_l][p_l];
  }
}

// bilinear meta for one (h, w, tap)
struct SMeta {
  float w00, w01, w10, w11;
  int i00, i01, i10, i11;
};
__device__ __forceinline__ SMeta meta_for(int h, int gw, int k, float oy, float ox) {
  SMeta m;
  const float py = (float)(h - 1 + k / 3) + oy;
  const float px = (float)(gw - 1 + k % 3) + ox;
  const float fy = floorf(py), fx = floorf(px);
  const float ly = py - fy, lx = px - fx;
  const int iy0 = (int)fy, ix0 = (int)fx;
  const float vy0 = (iy0 >= 0 && iy0 < 64) ? 1.f : 0.f;
  const float vy1 = (iy0 >= -1 && iy0 < 63) ? 1.f : 0.f;
  const float vx0 = (ix0 >= 0 && ix0 < 64) ? 1.f : 0.f;
  const float vx1 = (ix0 >= -1 && ix0 < 63) ? 1.f : 0.f;
  m.w00 = (1.f - ly) * (1.f - lx) * vy0 * vx0;
  m.w01 = (1.f - ly) * lx * vy0 * vx1;
  m.w10 = ly * (1.f - lx) * vy1 * vx0;
  m.w11 = ly * lx * vy1 * vx1;
  const int cy0 = min(max(iy0, 0), 63), cy1 = min(max(iy0 + 1, 0), 63);
  const int cx0 = min(max(ix0, 0), 63), cx1 = min(max(ix0 + 1, 0), 63);
  m.i00 = (cy0 * 64 + cx0) * 256;
  m.i01 = (cy0 * 64 + cx1) * 256;
  m.i10 = (cy1 * 64 + cx0) * 256;
  m.i11 = (cy1 * 64 + cx1) * 256;
  return m;
}

__device__ __forceinline__ unsigned lerp_pack(unsigned a, unsigned b, unsigned c, unsigned d,
                                              float w00, float w01, float w10, float w11) {
  float lo = w00 * bflo(a) + w01 * bflo(b) + w10 * bflo(c) + w11 * bflo(d);
  float hi = w00 * bfhi(a) + w01 * bfhi(b) + w10 * bfhi(c) + w11 * bfhi(d);
  return f2bf_bits(lo) | (f2bf_bits(hi) << 16);
}

// ---- K-half GEMM body: 18 chunks, chunk c: tap c>>2, cols (c&3)*64.
// dist-1 prefetch of gathers+B at period start; publish = __syncthreads()'s own
// vmcnt(0)+lgkm(0) drain (robust: no manual waitcnt ledger). NO setprio (T5 was
// null-to-negative here: R13 48.3->52.2us, VGPR 80->120).
template <int KH>
__device__ __forceinline__ void run_gemm(const float* __restrict__ offb,
                                         const ushort_t* __restrict__ xtb,
                                         const ushort_t* __restrict__ wb,
                                         ushort_t* Ab, ushort_t* Bb,
                                         int h, int s_w, int c8, int t,
                                         int wm, int wn, int wq, int wr,
                                         f32x4 (&acc)[2][4]) {
  float oy[5], ox[5];
  #pragma unroll
  for (int i = 0; i < 5; ++i) {
    oy[i] = offb[(2 * (KH * 4 + i)) * 4096];
    ox[i] = offb[(2 * (KH * 4 + i) + 1) * 4096];
  }

#define GATHER(N)                                                \
  {                                                              \
    const int c_ = KH * 18 + (N);                                \
    const int tap_ = c_ >> 2;                                    \
    const int loc_ = tap_ - KH * 4;                              \
    const int c0_ = (c_ & 3) << 6;                               \
    m = meta_for(h, s_w, tap_, oy[loc_], ox[loc_]);              \
    const int cc_ = c0_ + c8 * 8;                                \
    q00 = *(const uint4*)(xtb + m.i00 + cc_);                    \
    q01 = *(const uint4*)(xtb + m.i01 + cc_);                    \
    q10 = *(const uint4*)(xtb + m.i10 + cc_);                    \
    q11 = *(const uint4*)(xtb + m.i11 + cc_);                    \
  }

#define B_ISSUE(N, BUF)                                                                        \
  {                                                                                            \
    const int c_ = KH * 18 + (N);                                                              \
    const int tap_ = c_ >> 2;                                                                  \
    const int c0_ = (c_ & 3) << 6;                                                             \
    _Pragma("unroll") for (int i_ = 0; i_ < 4; ++i_) {                                         \
      const int idx_ = i_ * 512 + t;                                                           \
      const int row_ = idx_ >> 3, slot_ = idx_ & 7;                                            \
      const ushort_t* g_ = wb + (tap_ << 16) + row_ * 256 + c0_ + ((slot_ ^ (row_ & 7)) << 3); \
      __builtin_amdgcn_global_load_lds(                                                        \
          (gvoid_t*)g_, (lvoid_t*)((char*)Bb + (BUF) * 32768 + idx_ * 16), 16, 0, 0);          \
    }                                                                                          \
  }

#define A_WRITE(BUF)                                                         \
  {                                                                          \
    uint4 r;                                                                 \
    r.x = lerp_pack(q00.x, q01.x, q10.x, q11.x, m.w00, m.w01, m.w10, m.w11); \
    r.y = lerp_pack(q00.y, q01.y, q10.y, q11.y, m.w00, m.w01, m.w10, m.w11); \
    r.z = lerp_pack(q00.z, q01.z, q10.z, q11.z, m.w00, m.w01, m.w10, m.w11); \
    r.w = lerp_pack(q00.w, q01.w, q10.w, q11.w, m.w00, m.w01, m.w10, m.w11); \
    *(uint4*)&Ab[(BUF) * 4096 + s_w * 64 + ((c8 ^ (s_w & 7)) << 3)] = r;     \
  }

  {
    SMeta m;
    uint4 q00, q01, q10, q11;
    B_ISSUE(0, 0);
    GATHER(0);
    A_WRITE(0);
  }
  __syncthreads();

  #pragma unroll
  for (int n = 0; n < 18; ++n) {
    const int cur = n & 1;
    const int nb = cur ^ 1;
    SMeta m;
    uint4 q00, q01, q10, q11;
    if (n < 17) {
      B_ISSUE(n + 1, nb);
      GATHER(n + 1);
    }
    #pragma unroll
    for (int ks = 0; ks < 2; ++ks) {
      bf16x8 af[2], bfr[4];
      #pragma unroll
      for (int tm = 0; tm < 2; ++tm) {
        const int row = wm * 32 + tm * 16 + wr;
        const int slot = (ks * 4 + wq) ^ (row & 7);
        af[tm] = *(const bf16x8*)&Ab[cur * 4096 + row * 64 + slot * 8];
      }
      #pragma unroll
      for (int tn = 0; tn < 4; ++tn) {
        const int row = wn * 64 + tn * 16 + wr;
        const int slot = (ks * 4 + wq) ^ (row & 7);
        bfr[tn] = *(const bf16x8*)&Bb[cur * 16384 + row * 64 + slot * 8];
      }
      #pragma unroll
      for (int tm = 0; tm < 2; ++tm)
        #pragma unroll
        for (int tn = 0; tn < 4; ++tn)
          acc[tm][tn] =
              __builtin_amdgcn_mfma_f32_16x16x32_bf16(af[tm], bfr[tn], acc[tm][tn], 0, 0, 0);
    }
    if (n < 17) {
      A_WRITE(nb);
      __syncthreads();
    }
  }
#undef GATHER
#undef B_ISSUE
#undef A_WRITE
}

// ---------------- fused deform-sample + GEMM + split-K finisher ----------------
// grid = 512: rowid=bid&255 -> (b,h) XCD-swizzled; kh=bid>>8 (same XCD for both
// halves of a row). BM=64, BN=256, 8 waves, LDS 80KB -> 2 independent blocks/CU.
// Each block writes its bf16 partial, fences, bumps flags[row]; the SECOND block
// re-reads both partials (L2-hot, same XCD), combines in f32, folds GN stats,
// and writes the combined bf16 back into y0 in place. No extra kernel/launch.
__global__ __launch_bounds__(512) void k_gemm(const float* __restrict__ off,
                                              const ushort_t* __restrict__ xt,
                                              const ushort_t* __restrict__ wb,
                                              ushort_t* __restrict__ y0,
                                              ushort_t* __restrict__ y1,
                                              float* __restrict__ stats,
                                              int* __restrict__ flags) {
  __shared__ __attribute__((aligned(16))) ushort_t Abuf[2][64 * 64];   // 16KB
  __shared__ __attribute__((aligned(16))) ushort_t Bbuf[2][256 * 64];  // 64KB

  const int bid = blockIdx.x;  // 512
  const int rowid = bid & 255;
  const int kh = bid >> 8;
  const int lb = ((rowid & 7) << 5) | (rowid >> 3);  // XCD-contiguous (b,h)
  const int b = lb >> 6;
  const int h = lb & 63;
  const int t = threadIdx.x;
  const int wave = t >> 6;
  const int lane = t & 63;
  const int wq = lane >> 4;
  const int wr = lane & 15;
  const int wm = wave >> 2;
  const int wn = wave & 3;
  const int s_w = t >> 3;
  const int c8 = t & 7;

  const f32x4 zero = {0.f, 0.f, 0.f, 0.f};
  f32x4 acc[2][4];
  #pragma unroll
  for (int i = 0; i < 2; ++i)
    #pragma unroll
    for (int j = 0; j < 4; ++j) acc[i][j] = zero;

  const ushort_t* xtb = xt + (size_t)b * 4096 * 256;
  const float* offb = off + (size_t)b * 18 * 4096 + h * 64 + s_w;

  if (kh == 0)
    run_gemm<0>(offb, xtb, wb, &Abuf[0][0], &Bbuf[0][0], h, s_w, c8, t, wm, wn, wq, wr, acc);
  else
    run_gemm<1>(offb, xtb, wb, &Abuf[0][0], &Bbuf[0][0], h, s_w, c8, t, wm, wn, wq, wr, acc);

  // ---- epilogue: bf16 partial write [b][s][o] ----
  const size_t rowb = ((size_t)(b * 4096 + h * 64)) * 256;
  ushort_t* yb = (kh ? y1 : y0) + rowb;
  #pragma unroll
  for (int tm = 0; tm < 2; ++tm) {
    #pragma unroll
    for (int tn = 0; tn < 4; ++tn) {
      const int o = wn * 64 + tn * 16 + wr;
      #pragma unroll
      for (int r2 = 0; r2 < 4; ++r2) {
        const int ww = wm * 32 + tm * 16 + wq * 4 + r2;
        yb[ww * 256 + o] = f2bf(acc[tm][tn][r2]);
      }
    }
  }

  // ---- split-K finisher: second block of this row combines + stats ----
  __threadfence();  // release: partial visible before flag bump
  int* fsh = (int*)&Abuf[0][0];  // Abuf dead after main loop; reuse (LDS stays 80KB)
  if (t == 0) *fsh = atomicAdd(&flags[rowid], 1);
  __syncthreads();
  const int second = *fsh;
  if (second == 1) {
    __threadfence();  // acquire: see the other block's partial
    const int s_l = t >> 3;  // 0..63 (row s within this h-row)
    const int o8 = t & 7;    // 8-wide o subgroup
    #pragma unroll
    for (int ot = 0; ot < 4; ++ot) {
      const size_t adr = rowb + (size_t)s_l * 256 + ot * 64 + o8 * 8;
      const uint4 a = *(const uint4*)(y0 + adr);
      const uint4 c = *(const uint4*)(y1 + adr);
      float v[8];
      v[0] = bflo(a.x) + bflo(c.x); v[1] = bfhi(a.x) + bfhi(c.x);
      v[2] = bflo(a.y) + bflo(c.y); v[3] = bfhi(a.y) + bfhi(c.y);
      v[4] = bflo(a.z) + bflo(c.z); v[5] = bfhi(a.z) + bfhi(c.z);
      v[6] = bflo(a.w) + bflo(c.w); v[7] = bfhi(a.w) + bfhi(c.w);
      float sum = 0.f, ss = 0.f;
      #pragma unroll
      for (int j = 0; j < 8; ++j) {
        sum += v[j];
        ss += v[j] * v[j];
      }
      uint4 r;
      r.x = f2bf_bits(v[0]) | (f2bf_bits(v[1]) << 16);
      r.y = f2bf_bits(v[2]) | (f2bf_bits(v[3]) << 16);
      r.z = f2bf_bits(v[4]) | (f2bf_bits(v[5]) << 16);
      r.w = f2bf_bits(v[6]) | (f2bf_bits(v[7]) << 16);
      *(uint4*)(y0 + adr) = r;  // combined row back into y0, in place
      // fold lanes sharing o8 (xor bits 3..5), then 8 atomics per wave
      #pragma unroll
      for (int d = 8; d < 64; d <<= 1) {
        sum += __shfl_xor(sum, d, 64);
        ss += __shfl_xor(ss, d, 64);
      }
      if (lane < 8) {
        const int g = ot * 8 + lane;
        atomicAdd(&stats[(b * 32 + g) * 2], sum);
        atomicAdd(&stats[(b * 32 + g) * 2 + 1], ss);
      }
    }
  }
}

// ---------------- GN apply + ReLU: bf16 [b][s][o] -> f32 [b][o][s] ----------------
// Vectorized uint4 loads (8 bf16), normalize in f32, LDS-padded transpose,
// float4 stores.
__global__ __launch_bounds__(256) void k_apply(const ushort_t* __restrict__ yc,
                                               const float* __restrict__ stats,
                                               const float* __restrict__ gamma,
                                               const float* __restrict__ beta,
                                               float* __restrict__ out) {
  __shared__ float tile[64][65];
  const int bid = blockIdx.x;                    // 1024
  const int lb = ((bid & 7) << 7) | (bid >> 3);  // XCD-contiguous
  const int b = lb >> 8;
  const int st = (lb >> 2) & 63;
  const int ot = lb & 3;
  const int t = threadIdx.x;
  #pragma unroll
  for (int i = 0; i < 2; ++i) {
    const int u = t + 256 * i;
    const int s_l = u >> 3;
    const int o8 = u & 7;
    const size_t adr = ((size_t)(b * 4096 + st * 64 + s_l)) * 256 + ot * 64 + o8 * 8;
    const uint4 a = *(const uint4*)(yc + adr);
    float v[8];
    v[0] = bflo(a.x); v[1] = bfhi(a.x);
    v[2] = bflo(a.y); v[3] = bfhi(a.y);
    v[4] = bflo(a.z); v[5] = bfhi(a.z);
    v[6] = bflo(a.w); v[7] = bfhi(a.w);
    const int g = ot * 8 + o8;
    const float s1 = stats[(b * 32 + g) * 2];
    const float s2 = stats[(b * 32 + g) * 2 + 1];
    const float mean = s1 * (1.f / 32768.f);
    const float var = s2 * (1.f / 32768.f) - mean * mean;
    const float rstd = rsqrtf(var + 1e-5f);
    #pragma unroll
    for (int j = 0; j < 8; ++j) {
      const int o = ot * 64 + o8 * 8 + j;
      const float sc = rstd * gamma[o];
      const float sh = beta[o] - mean * sc;
      tile[s_l][o8 * 8 + j] = fmaxf(v[j] * sc + sh, 0.f);
    }
  }
  __syncthreads();
  #pragma unroll
  for (int i = 0; i < 2; ++i) {
    const int u = t + 256 * i;
    const int o_l = u >> 3;
    const int s8 = u & 7;
    float4 f0, f1;
    f0.x = tile[s8 * 8 + 0][o_l];
    f0.y = tile[s8 * 8 + 1][o_l];
    f0.z = tile[s8 * 8 + 2][o_l];
    f0.w = tile[s8 * 8 + 3][o_l];
    f1.x = tile[s8 * 8 + 4][o_l];
    f1.y = tile[s8 * 8 + 5][o_l];
    f1.z = tile[s8 * 8 + 6][o_l];
    f1.w = tile[s8 * 8 + 7][o_l];
    float* ob = out + ((size_t)(b * 256 + ot * 64 + o_l)) * 4096 + st * 64 + s8 * 8;
    *(float4*)ob = f0;
    *(float4*)(ob + 4) = f1;
  }
}

extern "C" void kernel_launch(void* const* d_in, const int* in_sizes, int n_in,
                              void* d_out, int out_size, void* d_ws, size_t ws_size,
                              hipStream_t stream) {
  const float* x = (const float*)d_in[0];       // (4,256,64,64)
  const float* off = (const float*)d_in[1];     // (4,18,64,64)
  const float* w = (const float*)d_in[2];       // (256,256,3,3)
  const float* gamma = (const float*)d_in[3];   // (256)
  const float* beta = (const float*)d_in[4];    // (256)
  float* out = (float*)d_out;

  char* ws = (char*)d_ws;
  ushort_t* y0 = (ushort_t*)(ws);                 //  8,388,608 B  partial kh=0 / combined
  ushort_t* y1 = (ushort_t*)(ws + 8388608);       //  8,388,608 B  partial kh=1
  ushort_t* xt = (ushort_t*)(ws + 16777216);      //  8,388,608 B  [b][h][w][c] bf16
  ushort_t* wb = (ushort_t*)(ws + 25165824);      //  1,179,648 B  [k][o][c] bf16
  float* stats = (float*)(ws + 26345472);         //      1,024 B  [b][g]{sum,ss}
  int* flags = (int*)(ws + 26346496);             //      1,024 B  per-row split-K flags

  k_prep<<<1280, 256, 0, stream>>>(x, w, xt, wb, stats, flags);
  k_gemm<<<512, 512, 0, stream>>>(off, xt, wb, y0, y1, stats, flags);
  k_apply<<<1024, 256, 0, stream>>>(y0, stats, gamma, beta, out);
}

// Round 15
// 81.549 us; speedup vs baseline: 2.9483x; 2.9483x over previous
//
#include <hip/hip_runtime.h>

typedef unsigned short ushort_t;
typedef __bf16 bf16x8 __attribute__((ext_vector_type(8)));
typedef float f32x4 __attribute__((ext_vector_type(4)));
typedef void __attribute__((address_space(1))) gvoid_t;
typedef void __attribute__((address_space(3))) lvoid_t;

__device__ __forceinline__ float bflo(unsigned u) { return __builtin_bit_cast(float, u << 16); }
__device__ __forceinline__ float bfhi(unsigned u) { return __builtin_bit_cast(float, u & 0xffff0000u); }
__device__ __forceinline__ unsigned f2bf_bits(float f) {
  unsigned u = __builtin_bit_cast(unsigned, f);
  return (u + 0x7fffu + ((u >> 16) & 1u)) >> 16;
}
__device__ __forceinline__ ushort_t f2bf(float f) { return (ushort_t)f2bf_bits(f); }

// ---------------- fused prep: x-transpose + w-pack + stats zero (1 launch) ----------------
// blocks 0..1023:  x (b,c,h,w) f32 -> xt[b][h][w][c] bf16
// blocks 1024..1279: w (o,c,k) f32 -> wb[k][o][c] bf16; block 1024 zeroes stats.
__global__ __launch_bounds__(256) void k_prep(const float* __restrict__ x,
                                              const float* __restrict__ w,
                                              ushort_t* __restrict__ xt,
                                              ushort_t* __restrict__ wb,
                                              float* __restrict__ stats) {
  const int gid = blockIdx.x;  // 1280
  const int t = threadIdx.x;
  if (gid >= 1024) {
    if (gid == 1024) stats[t] = 0.f;  // 256 floats = 4b x 32g x {sum,ss}
    const int idx = (gid - 1024) * 256 + t;  // (o,c) pair
    const float* src = w + (size_t)idx * 9;
    #pragma unroll
    for (int k = 0; k < 9; ++k)
      wb[(k << 16) + idx] = f2bf(src[k]);
    return;
  }
  __shared__ ushort_t tile[64][68];
  const int b = gid >> 8;
  const int ct = (gid >> 6) & 3;
  const int pt = gid & 63;
  const float* xb = x + ((size_t)(b * 256 + ct * 64)) * 4096 + pt * 64;
  #pragma unroll
  for (int i = 0; i < 16; ++i) {
    const int idx = t + 256 * i;
    const int c_l = idx >> 6, p_l = idx & 63;
    tile[c_l][p_l] = f2bf(xb[(size_t)c_l * 4096 + p_l]);
  }
  __syncthreads();
  ushort_t* xo = xt + ((size_t)(b * 4096 + pt * 64)) * 256 + ct * 64;
  #pragma unroll
  for (int i = 0; i < 16; ++i) {
    const int idx = t + 256 * i;
    const int p_l = idx >> 6, c_l = idx & 63;
    xo[(size_t)p_l * 256 + c_l] = tile[c_l][p_l];
  }
}

// bilinear meta for one (h, w, tap)
struct SMeta {
  float w00, w01, w10, w11;
  int i00, i01, i10, i11;
};
__device__ __forceinline__ SMeta meta_for(int h, int gw, int k, float oy, float ox) {
  SMeta m;
  const float py = (float)(h - 1 + k / 3) + oy;
  const float px = (float)(gw - 1 + k % 3) + ox;
  const float fy = floorf(py), fx = floorf(px);
  const float ly = py - fy, lx = px - fx;
  const int iy0 = (int)fy, ix0 = (int)fx;
  const float vy0 = (iy0 >= 0 && iy0 < 64) ? 1.f : 0.f;
  const float vy1 = (iy0 >= -1 && iy0 < 63) ? 1.f : 0.f;
  const float vx0 = (ix0 >= 0 && ix0 < 64) ? 1.f : 0.f;
  const float vx1 = (ix0 >= -1 && ix0 < 63) ? 1.f : 0.f;
  m.w00 = (1.f - ly) * (1.f - lx) * vy0 * vx0;
  m.w01 = (1.f - ly) * lx * vy0 * vx1;
  m.w10 = ly * (1.f - lx) * vy1 * vx0;
  m.w11 = ly * lx * vy1 * vx1;
  const int cy0 = min(max(iy0, 0), 63), cy1 = min(max(iy0 + 1, 0), 63);
  const int cx0 = min(max(ix0, 0), 63), cx1 = min(max(ix0 + 1, 0), 63);
  m.i00 = (cy0 * 64 + cx0) * 256;
  m.i01 = (cy0 * 64 + cx1) * 256;
  m.i10 = (cy1 * 64 + cx0) * 256;
  m.i11 = (cy1 * 64 + cx1) * 256;
  return m;
}

__device__ __forceinline__ unsigned lerp_pack(unsigned a, unsigned b, unsigned c, unsigned d,
                                              float w00, float w01, float w10, float w11) {
  float lo = w00 * bflo(a) + w01 * bflo(b) + w10 * bflo(c) + w11 * bflo(d);
  float hi = w00 * bfhi(a) + w01 * bfhi(b) + w10 * bfhi(c) + w11 * bfhi(d);
  return f2bf_bits(lo) | (f2bf_bits(hi) << 16);
}

// ---- K-half GEMM body: 18 chunks, chunk c: tap c>>2, cols (c&3)*64.
// dist-1 prefetch of gathers+B at period start; publish = __syncthreads()'s own
// vmcnt(0)+lgkm(0) drain (robust: no manual waitcnt ledger). NO setprio (T5 was
// null-to-negative off 8-phase structures: R13 48.3->52.2us, VGPR 80->120).
// NO in-kernel split-K handoff (R14: device-scope fences = L2 writeback storm,
// 48->228us — the kernel boundary is the cheap fence on CDNA4).
template <int KH>
__device__ __forceinline__ void run_gemm(const float* __restrict__ offb,
                                         const ushort_t* __restrict__ xtb,
                                         const ushort_t* __restrict__ wb,
                                         ushort_t* Ab, ushort_t* Bb,
                                         int h, int s_w, int c8, int t,
                                         int wm, int wn, int wq, int wr,
                                         f32x4 (&acc)[2][4]) {
  float oy[5], ox[5];
  #pragma unroll
  for (int i = 0; i < 5; ++i) {
    oy[i] = offb[(2 * (KH * 4 + i)) * 4096];
    ox[i] = offb[(2 * (KH * 4 + i) + 1) * 4096];
  }

#define GATHER(N)                                                \
  {                                                              \
    const int c_ = KH * 18 + (N);                                \
    const int tap_ = c_ >> 2;                                    \
    const int loc_ = tap_ - KH * 4;                              \
    const int c0_ = (c_ & 3) << 6;                               \
    m = meta_for(h, s_w, tap_, oy[loc_], ox[loc_]);              \
    const int cc_ = c0_ + c8 * 8;                                \
    q00 = *(const uint4*)(xtb + m.i00 + cc_);                    \
    q01 = *(const uint4*)(xtb + m.i01 + cc_);                    \
    q10 = *(const uint4*)(xtb + m.i10 + cc_);                    \
    q11 = *(const uint4*)(xtb + m.i11 + cc_);                    \
  }

#define B_ISSUE(N, BUF)                                                                        \
  {                                                                                            \
    const int c_ = KH * 18 + (N);                                                              \
    const int tap_ = c_ >> 2;                                                                  \
    const int c0_ = (c_ & 3) << 6;                                                             \
    _Pragma("unroll") for (int i_ = 0; i_ < 4; ++i_) {                                         \
      const int idx_ = i_ * 512 + t;                                                           \
      const int row_ = idx_ >> 3, slot_ = idx_ & 7;                                            \
      const ushort_t* g_ = wb + (tap_ << 16) + row_ * 256 + c0_ + ((slot_ ^ (row_ & 7)) << 3); \
      __builtin_amdgcn_global_load_lds(                                                        \
          (gvoid_t*)g_, (lvoid_t*)((char*)Bb + (BUF) * 32768 + idx_ * 16), 16, 0, 0);          \
    }                                                                                          \
  }

#define A_WRITE(BUF)                                                         \
  {                                                                          \
    uint4 r;                                                                 \
    r.x = lerp_pack(q00.x, q01.x, q10.x, q11.x, m.w00, m.w01, m.w10, m.w11); \
    r.y = lerp_pack(q00.y, q01.y, q10.y, q11.y, m.w00, m.w01, m.w10, m.w11); \
    r.z = lerp_pack(q00.z, q01.z, q10.z, q11.z, m.w00, m.w01, m.w10, m.w11); \
    r.w = lerp_pack(q00.w, q01.w, q10.w, q11.w, m.w00, m.w01, m.w10, m.w11); \
    *(uint4*)&Ab[(BUF) * 4096 + s_w * 64 + ((c8 ^ (s_w & 7)) << 3)] = r;     \
  }

  {
    SMeta m;
    uint4 q00, q01, q10, q11;
    B_ISSUE(0, 0);
    GATHER(0);
    A_WRITE(0);
  }
  __syncthreads();

  #pragma unroll
  for (int n = 0; n < 18; ++n) {
    const int cur = n & 1;
    const int nb = cur ^ 1;
    SMeta m;
    uint4 q00, q01, q10, q11;
    if (n < 17) {
      B_ISSUE(n + 1, nb);
      GATHER(n + 1);
    }
    #pragma unroll
    for (int ks = 0; ks < 2; ++ks) {
      bf16x8 af[2], bfr[4];
      #pragma unroll
      for (int tm = 0; tm < 2; ++tm) {
        const int row = wm * 32 + tm * 16 + wr;
        const int slot = (ks * 4 + wq) ^ (row & 7);
        af[tm] = *(const bf16x8*)&Ab[cur * 4096 + row * 64 + slot * 8];
      }
      #pragma unroll
      for (int tn = 0; tn < 4; ++tn) {
        const int row = wn * 64 + tn * 16 + wr;
        const int slot = (ks * 4 + wq) ^ (row & 7);
        bfr[tn] = *(const bf16x8*)&Bb[cur * 16384 + row * 64 + slot * 8];
      }
      #pragma unroll
      for (int tm = 0; tm < 2; ++tm)
        #pragma unroll
        for (int tn = 0; tn < 4; ++tn)
          acc[tm][tn] =
              __builtin_amdgcn_mfma_f32_16x16x32_bf16(af[tm], bfr[tn], acc[tm][tn], 0, 0, 0);
    }
    if (n < 17) {
      A_WRITE(nb);
      __syncthreads();
    }
  }
#undef GATHER
#undef B_ISSUE
#undef A_WRITE
}

// ---------------- fused deform-sample + GEMM, K-split bf16 partials ----------------
// grid = 512: rowid=bid&255 -> (b,h) XCD-swizzled; kh=bid>>8. BM=64, BN=256,
// 8 waves. LDS 80KB -> 2 INDEPENDENT blocks/CU (m114 overlap mechanism).
__global__ __launch_bounds__(512) void k_gemm(const float* __restrict__ off,
                                              const ushort_t* __restrict__ xt,
                                              const ushort_t* __restrict__ wb,
                                              ushort_t* __restrict__ y0,
                                              ushort_t* __restrict__ y1) {
  __shared__ __attribute__((aligned(16))) ushort_t Abuf[2][64 * 64];   // 16KB
  __shared__ __attribute__((aligned(16))) ushort_t Bbuf[2][256 * 64];  // 64KB

  const int bid = blockIdx.x;  // 512
  const int rowid = bid & 255;
  const int kh = bid >> 8;
  const int lb = ((rowid & 7) << 5) | (rowid >> 3);  // XCD-contiguous (b,h)
  const int b = lb >> 6;
  const int h = lb & 63;
  const int t = threadIdx.x;
  const int wave = t >> 6;
  const int lane = t & 63;
  const int wq = lane >> 4;
  const int wr = lane & 15;
  const int wm = wave >> 2;
  const int wn = wave & 3;
  const int s_w = t >> 3;
  const int c8 = t & 7;

  const f32x4 zero = {0.f, 0.f, 0.f, 0.f};
  f32x4 acc[2][4];
  #pragma unroll
  for (int i = 0; i < 2; ++i)
    #pragma unroll
    for (int j = 0; j < 4; ++j) acc[i][j] = zero;

  const ushort_t* xtb = xt + (size_t)b * 4096 * 256;
  const float* offb = off + (size_t)b * 18 * 4096 + h * 64 + s_w;

  if (kh == 0)
    run_gemm<0>(offb, xtb, wb, &Abuf[0][0], &Bbuf[0][0], h, s_w, c8, t, wm, wn, wq, wr, acc);
  else
    run_gemm<1>(offb, xtb, wb, &Abuf[0][0], &Bbuf[0][0], h, s_w, c8, t, wm, wn, wq, wr, acc);

  ushort_t* yb = (kh ? y1 : y0) + ((size_t)(b * 4096 + h * 64)) * 256;
  #pragma unroll
  for (int tm = 0; tm < 2; ++tm) {
    #pragma unroll
    for (int tn = 0; tn < 4; ++tn) {
      const int o = wn * 64 + tn * 16 + wr;
      #pragma unroll
      for (int r2 = 0; r2 < 4; ++r2) {
        const int ww = wm * 32 + tm * 16 + wq * 4 + r2;
        yb[ww * 256 + o] = f2bf(acc[tm][tn][r2]);
      }
    }
  }
}

// ---------------- combine partials + GN stats + transpose to [b][o][s] ----------------
// block = (b, st, ot): 64s x 64o tile. Vectorized uint4 reads of y0,y1 (8 bf16),
// f32 add, stats partials (each uint4 spans exactly one 8-wide o-group),
// LDS transpose, write yc[b][o][s] bf16 (apply becomes pure streaming).
__global__ __launch_bounds__(256) void k_comb(const ushort_t* __restrict__ y0,
                                              const ushort_t* __restrict__ y1,
                                              ushort_t* __restrict__ yc,
                                              float* __restrict__ stats) {
  __shared__ float tile[64][65];
  const int bid = blockIdx.x;                    // 1024
  const int lb = ((bid & 7) << 7) | (bid >> 3);  // XCD-contiguous
  const int b = lb >> 8;
  const int st = (lb >> 2) & 63;
  const int ot = lb & 3;
  const int t = threadIdx.x;
  const size_t ybase = ((size_t)(b * 4096 + st * 64)) * 256 + ot * 64;
  float sum = 0.f, ss = 0.f;
  #pragma unroll
  for (int i = 0; i < 2; ++i) {
    const int u = t + 256 * i;
    const int s_l = u >> 3;  // 0..63
    const int o8 = u & 7;    // 8-wide o-subgroup
    const size_t adr = ybase + (size_t)s_l * 256 + o8 * 8;
    const uint4 a = *(const uint4*)(y0 + adr);
    const uint4 c = *(const uint4*)(y1 + adr);
    float v[8];
    v[0] = bflo(a.x) + bflo(c.x); v[1] = bfhi(a.x) + bfhi(c.x);
    v[2] = bflo(a.y) + bflo(c.y); v[3] = bfhi(a.y) + bfhi(c.y);
    v[4] = bflo(a.z) + bflo(c.z); v[5] = bfhi(a.z) + bfhi(c.z);
    v[6] = bflo(a.w) + bflo(c.w); v[7] = bfhi(a.w) + bfhi(c.w);
    #pragma unroll
    for (int j = 0; j < 8; ++j) {
      sum += v[j];
      ss += v[j] * v[j];
      tile[s_l][o8 * 8 + j] = v[j];
    }
  }
  // group of this thread = ot*8 + (t&7); fold lanes differing in bits 3,4,5
  #pragma unroll
  for (int d = 8; d < 64; d <<= 1) {
    sum += __shfl_xor(sum, d, 64);
    ss += __shfl_xor(ss, d, 64);
  }
  if ((t & 63) < 8) {
    const int g = ot * 8 + (t & 7);
    atomicAdd(&stats[(b * 32 + g) * 2], sum);
    atomicAdd(&stats[(b * 32 + g) * 2 + 1], ss);
  }
  __syncthreads();
  // transposed write: 8 s per thread for one o
  #pragma unroll
  for (int i = 0; i < 2; ++i) {
    const int u = t + 256 * i;
    const int o_l = u >> 3;  // 0..63
    const int s8 = u & 7;
    float v[8];
    #pragma unroll
    for (int j = 0; j < 8; ++j) v[j] = tile[s8 * 8 + j][o_l];
    uint4 r;
    r.x = f2bf_bits(v[0]) | (f2bf_bits(v[1]) << 16);
    r.y = f2bf_bits(v[2]) | (f2bf_bits(v[3]) << 16);
    r.z = f2bf_bits(v[4]) | (f2bf_bits(v[5]) << 16);
    r.w = f2bf_bits(v[6]) | (f2bf_bits(v[7]) << 16);
    *(uint4*)(yc + ((size_t)(b * 256 + ot * 64 + o_l)) * 4096 + st * 64 + s8 * 8) = r;
  }
}

// ---------------- GN apply + ReLU: pure streaming over [b][o][s] ----------------
__global__ __launch_bounds__(256) void k_apply(const ushort_t* __restrict__ yc,
                                               const float* __restrict__ stats,
                                               const float* __restrict__ gamma,
                                               const float* __restrict__ beta,
                                               float* __restrict__ out) {
  const int bid = blockIdx.x;                    // 2048
  const int lb = ((bid & 7) << 8) | (bid >> 3);  // XCD-contiguous
  const size_t base = (size_t)lb * 2048 + threadIdx.x * 8;  // element index
  const int b = (int)(base >> 20);
  const int o = (int)((base >> 12) & 255);
  const int g = o >> 3;
  const float s1 = stats[(b * 32 + g) * 2];
  const float s2 = stats[(b * 32 + g) * 2 + 1];
  const float mean = s1 * (1.f / 32768.f);
  const float var = s2 * (1.f / 32768.f) - mean * mean;
  const float rstd = rsqrtf(var + 1e-5f);
  const float sc = rstd * gamma[o];
  const float sh = beta[o] - mean * sc;
  const uint4 a = *(const uint4*)(yc + base);
  float v[8];
  v[0] = bflo(a.x); v[1] = bfhi(a.x);
  v[2] = bflo(a.y); v[3] = bfhi(a.y);
  v[4] = bflo(a.z); v[5] = bfhi(a.z);
  v[6] = bflo(a.w); v[7] = bfhi(a.w);
  float4 f0, f1;
  f0.x = fmaxf(v[0] * sc + sh, 0.f);
  f0.y = fmaxf(v[1] * sc + sh, 0.f);
  f0.z = fmaxf(v[2] * sc + sh, 0.f);
  f0.w = fmaxf(v[3] * sc + sh, 0.f);
  f1.x = fmaxf(v[4] * sc + sh, 0.f);
  f1.y = fmaxf(v[5] * sc + sh, 0.f);
  f1.z = fmaxf(v[6] * sc + sh, 0.f);
  f1.w = fmaxf(v[7] * sc + sh, 0.f);
  *(float4*)(out + base) = f0;
  *(float4*)(out + base + 4) = f1;
}

extern "C" void kernel_launch(void* const* d_in, const int* in_sizes, int n_in,
                              void* d_out, int out_size, void* d_ws, size_t ws_size,
                              hipStream_t stream) {
  const float* x = (const float*)d_in[0];       // (4,256,64,64)
  const float* off = (const float*)d_in[1];     // (4,18,64,64)
  const float* w = (const float*)d_in[2];       // (256,256,3,3)
  const float* gamma = (const float*)d_in[3];   // (256)
  const float* beta = (const float*)d_in[4];    // (256)
  float* out = (float*)d_out;

  char* ws = (char*)d_ws;
  ushort_t* y0 = (ushort_t*)(ws);                 //  8,388,608 B  partial kh=0, bf16
  ushort_t* y1 = (ushort_t*)(ws + 8388608);       //  8,388,608 B  partial kh=1, bf16
  ushort_t* xt = (ushort_t*)(ws + 16777216);      //  8,388,608 B  [b][h][w][c] bf16
  ushort_t* yc = xt;                              //  reuses xt region after gemm
  ushort_t* wb = (ushort_t*)(ws + 25165824);      //  1,179,648 B  [k][o][c] bf16
  float* stats = (float*)(ws + 26345472);         //      1,024 B  [b][g]{sum,ss}

  k_prep<<<1280, 256, 0, stream>>>(x, w, xt, wb, stats);
  k_gemm<<<512, 512, 0, stream>>>(off, xt, wb, y0, y1);
  k_comb<<<1024, 256, 0, stream>>>(y0, y1, yc, stats);
  k_apply<<<2048, 256, 0, stream>>>(yc, stats, gamma, beta, out);
}

// Round 16
// 81.046 us; speedup vs baseline: 2.9667x; 1.0062x over previous
//
#include <hip/hip_runtime.h>

typedef unsigned short ushort_t;
typedef __bf16 bf16x8 __attribute__((ext_vector_type(8)));
typedef float f32x4 __attribute__((ext_vector_type(4)));
typedef void __attribute__((address_space(1))) gvoid_t;
typedef void __attribute__((address_space(3))) lvoid_t;

__device__ __forceinline__ float bflo(unsigned u) { return __builtin_bit_cast(float, u << 16); }
__device__ __forceinline__ float bfhi(unsigned u) { return __builtin_bit_cast(float, u & 0xffff0000u); }
__device__ __forceinline__ unsigned f2bf_bits(float f) {
  unsigned u = __builtin_bit_cast(unsigned, f);
  return (u + 0x7fffu + ((u >> 16) & 1u)) >> 16;
}
__device__ __forceinline__ ushort_t f2bf(float f) { return (ushort_t)f2bf_bits(f); }

// ---------------- fused prep: x-transpose + w-pack + stats zero (1 launch) ----------------
// blocks 0..1023:  x (b,c,h,w) f32 -> xt[b][h][w][c] bf16 (float4 loads, uint4 stores)
// blocks 1024..1279: w (o,c,k) f32 -> wb[k][o][c] bf16; block 1024 zeroes stats.
__global__ __launch_bounds__(256) void k_prep(const float* __restrict__ x,
                                              const float* __restrict__ w,
                                              ushort_t* __restrict__ xt,
                                              ushort_t* __restrict__ wb,
                                              float* __restrict__ stats) {
  const int gid = blockIdx.x;  // 1280
  const int t = threadIdx.x;
  if (gid >= 1024) {
    if (gid == 1024) stats[t] = 0.f;  // 256 floats = 4b x 32g x {sum,ss}
    const int idx = (gid - 1024) * 256 + t;  // (o,c) pair
    const float* src = w + (size_t)idx * 9;
    const float4 a = *(const float4*)(src);
    const float4 b4 = *(const float4*)(src + 4);
    const float c8v = src[8];
    wb[(0 << 16) + idx] = f2bf(a.x);
    wb[(1 << 16) + idx] = f2bf(a.y);
    wb[(2 << 16) + idx] = f2bf(a.z);
    wb[(3 << 16) + idx] = f2bf(a.w);
    wb[(4 << 16) + idx] = f2bf(b4.x);
    wb[(5 << 16) + idx] = f2bf(b4.y);
    wb[(6 << 16) + idx] = f2bf(b4.z);
    wb[(7 << 16) + idx] = f2bf(b4.w);
    wb[(8 << 16) + idx] = f2bf(c8v);
    return;
  }
  __shared__ __attribute__((aligned(16))) ushort_t tile[64][68];
  const int b = gid >> 8;
  const int ct = (gid >> 6) & 3;
  const int pt = gid & 63;
  const float* xb = x + ((size_t)(b * 256 + ct * 64)) * 4096 + pt * 64;
  // fill: float4 loads (c_l row, 4 consecutive p), pack 4 bf16 -> one 8B LDS write
  #pragma unroll
  for (int i = 0; i < 4; ++i) {
    const int idx = t + 256 * i;       // 0..1023
    const int c_l = idx >> 4;          // 0..63
    const int p4 = (idx & 15) * 4;     // 0..60
    const float4 v = *(const float4*)(xb + (size_t)c_l * 4096 + p4);
    uint2 pk;
    pk.x = f2bf_bits(v.x) | (f2bf_bits(v.y) << 16);
    pk.y = f2bf_bits(v.z) | (f2bf_bits(v.w) << 16);
    *(uint2*)&tile[c_l][p4] = pk;
  }
  __syncthreads();
  // store: each thread writes 8 consecutive c (one uint4) for one p
  ushort_t* xo = xt + ((size_t)(b * 4096 + pt * 64)) * 256 + ct * 64;
  #pragma unroll
  for (int i = 0; i < 2; ++i) {
    const int u = t + 256 * i;   // 0..511
    const int p_l = u >> 3;      // 0..63
    const int c8 = u & 7;        // 8-wide c group
    uint4 r;
    r.x = (unsigned)tile[c8 * 8 + 0][p_l] | ((unsigned)tile[c8 * 8 + 1][p_l] << 16);
    r.y = (unsigned)tile[c8 * 8 + 2][p_l] | ((unsigned)tile[c8 * 8 + 3][p_l] << 16);
    r.z = (unsigned)tile[c8 * 8 + 4][p_l] | ((unsigned)tile[c8 * 8 + 5][p_l] << 16);
    r.w = (unsigned)tile[c8 * 8 + 6][p_l] | ((unsigned)tile[c8 * 8 + 7][p_l] << 16);
    *(uint4*)(xo + (size_t)p_l * 256 + c8 * 8) = r;
  }
}

// bilinear meta for one (h, w, tap)
struct SMeta {
  float w00, w01, w10, w11;
  int i00, i01, i10, i11;
};
__device__ __forceinline__ SMeta meta_for(int h, int gw, int k, float oy, float ox) {
  SMeta m;
  const float py = (float)(h - 1 + k / 3) + oy;
  const float px = (float)(gw - 1 + k % 3) + ox;
  const float fy = floorf(py), fx = floorf(px);
  const float ly = py - fy, lx = px - fx;
  const int iy0 = (int)fy, ix0 = (int)fx;
  const float vy0 = (iy0 >= 0 && iy0 < 64) ? 1.f : 0.f;
  const float vy1 = (iy0 >= -1 && iy0 < 63) ? 1.f : 0.f;
  const float vx0 = (ix0 >= 0 && ix0 < 64) ? 1.f : 0.f;
  const float vx1 = (ix0 >= -1 && ix0 < 63) ? 1.f : 0.f;
  m.w00 = (1.f - ly) * (1.f - lx) * vy0 * vx0;
  m.w01 = (1.f - ly) * lx * vy0 * vx1;
  m.w10 = ly * (1.f - lx) * vy1 * vx0;
  m.w11 = ly * lx * vy1 * vx1;
  const int cy0 = min(max(iy0, 0), 63), cy1 = min(max(iy0 + 1, 0), 63);
  const int cx0 = min(max(ix0, 0), 63), cx1 = min(max(ix0 + 1, 0), 63);
  m.i00 = (cy0 * 64 + cx0) * 256;
  m.i01 = (cy0 * 64 + cx1) * 256;
  m.i10 = (cy1 * 64 + cx0) * 256;
  m.i11 = (cy1 * 64 + cx1) * 256;
  return m;
}

__device__ __forceinline__ unsigned lerp_pack(unsigned a, unsigned b, unsigned c, unsigned d,
                                              float w00, float w01, float w10, float w11) {
  float lo = w00 * bflo(a) + w01 * bflo(b) + w10 * bflo(c) + w11 * bflo(d);
  float hi = w00 * bfhi(a) + w01 * bfhi(b) + w10 * bfhi(c) + w11 * bfhi(d);
  return f2bf_bits(lo) | (f2bf_bits(hi) << 16);
}

// ---- K-half GEMM body: 18 chunks, chunk c: tap c>>2, cols (c&3)*64.
// dist-1 prefetch of gathers+B at period start; publish = __syncthreads()'s own
// vmcnt(0)+lgkm(0) drain (robust: no manual waitcnt ledger). NO setprio (T5 was
// null-to-negative off 8-phase structures: R13 48.3->52.2us, VGPR 80->120).
// NO in-kernel split-K handoff (R14: device-scope fences = L2 writeback storm,
// 48->228us — the kernel boundary is the cheap fence on CDNA4).
template <int KH>
__device__ __forceinline__ void run_gemm(const float* __restrict__ offb,
                                         const ushort_t* __restrict__ xtb,
                                         const ushort_t* __restrict__ wb,
                                         ushort_t* Ab, ushort_t* Bb,
                                         int h, int s_w, int c8, int t,
                                         int wm, int wn, int wq, int wr,
                                         f32x4 (&acc)[2][4]) {
  float oy[5], ox[5];
  #pragma unroll
  for (int i = 0; i < 5; ++i) {
    oy[i] = offb[(2 * (KH * 4 + i)) * 4096];
    ox[i] = offb[(2 * (KH * 4 + i) + 1) * 4096];
  }

#define GATHER(N)                                                \
  {                                                              \
    const int c_ = KH * 18 + (N);                                \
    const int tap_ = c_ >> 2;                                    \
    const int loc_ = tap_ - KH * 4;                              \
    const int c0_ = (c_ & 3) << 6;                               \
    m = meta_for(h, s_w, tap_, oy[loc_], ox[loc_]);              \
    const int cc_ = c0_ + c8 * 8;                                \
    q00 = *(const uint4*)(xtb + m.i00 + cc_);                    \
    q01 = *(const uint4*)(xtb + m.i01 + cc_);                    \
    q10 = *(const uint4*)(xtb + m.i10 + cc_);                    \
    q11 = *(const uint4*)(xtb + m.i11 + cc_);                    \
  }

#define B_ISSUE(N, BUF)                                                                        \
  {                                                                                            \
    const int c_ = KH * 18 + (N);                                                              \
    const int tap_ = c_ >> 2;                                                                  \
    const int c0_ = (c_ & 3) << 6;                                                             \
    _Pragma("unroll") for (int i_ = 0; i_ < 4; ++i_) {                                         \
      const int idx_ = i_ * 512 + t;                                                           \
      const int row_ = idx_ >> 3, slot_ = idx_ & 7;                                            \
      const ushort_t* g_ = wb + (tap_ << 16) + row_ * 256 + c0_ + ((slot_ ^ (row_ & 7)) << 3); \
      __builtin_amdgcn_global_load_lds(                                                        \
          (gvoid_t*)g_, (lvoid_t*)((char*)Bb + (BUF) * 32768 + idx_ * 16), 16, 0, 0);          \
    }                                                                                          \
  }

#define A_WRITE(BUF)                                                         \
  {                                                                          \
    uint4 r;                                                                 \
    r.x = lerp_pack(q00.x, q01.x, q10.x, q11.x, m.w00, m.w01, m.w10, m.w11); \
    r.y = lerp_pack(q00.y, q01.y, q10.y, q11.y, m.w00, m.w01, m.w10, m.w11); \
    r.z = lerp_pack(q00.z, q01.z, q10.z, q11.z, m.w00, m.w01, m.w10, m.w11); \
    r.w = lerp_pack(q00.w, q01.w, q10.w, q11.w, m.w00, m.w01, m.w10, m.w11); \
    *(uint4*)&Ab[(BUF) * 4096 + s_w * 64 + ((c8 ^ (s_w & 7)) << 3)] = r;     \
  }

  {
    SMeta m;
    uint4 q00, q01, q10, q11;
    B_ISSUE(0, 0);
    GATHER(0);
    A_WRITE(0);
  }
  __syncthreads();

  #pragma unroll
  for (int n = 0; n < 18; ++n) {
    const int cur = n & 1;
    const int nb = cur ^ 1;
    SMeta m;
    uint4 q00, q01, q10, q11;
    if (n < 17) {
      B_ISSUE(n + 1, nb);
      GATHER(n + 1);
    }
    #pragma unroll
    for (int ks = 0; ks < 2; ++ks) {
      bf16x8 af[2], bfr[4];
      #pragma unroll
      for (int tm = 0; tm < 2; ++tm) {
        const int row = wm * 32 + tm * 16 + wr;
        const int slot = (ks * 4 + wq) ^ (row & 7);
        af[tm] = *(const bf16x8*)&Ab[cur * 4096 + row * 64 + slot * 8];
      }
      #pragma unroll
      for (int tn = 0; tn < 4; ++tn) {
        const int row = wn * 64 + tn * 16 + wr;
        const int slot = (ks * 4 + wq) ^ (row & 7);
        bfr[tn] = *(const bf16x8*)&Bb[cur * 16384 + row * 64 + slot * 8];
      }
      #pragma unroll
      for (int tm = 0; tm < 2; ++tm)
        #pragma unroll
        for (int tn = 0; tn < 4; ++tn)
          acc[tm][tn] =
              __builtin_amdgcn_mfma_f32_16x16x32_bf16(af[tm], bfr[tn], acc[tm][tn], 0, 0, 0);
    }
    if (n < 17) {
      A_WRITE(nb);
      __syncthreads();
    }
  }
#undef GATHER
#undef B_ISSUE
#undef A_WRITE
}

// ---------------- fused deform-sample + GEMM, K-split bf16 partials ----------------
// grid = 512: rowid=bid&255 -> (b,h) XCD-swizzled; kh=bid>>8. BM=64, BN=256,
// 8 waves. LDS 80KB -> 2 INDEPENDENT blocks/CU (m114 overlap mechanism).
__global__ __launch_bounds__(512) void k_gemm(const float* __restrict__ off,
                                              const ushort_t* __restrict__ xt,
                                              const ushort_t* __restrict__ wb,
                                              ushort_t* __restrict__ y0,
                                              ushort_t* __restrict__ y1) {
  __shared__ __attribute__((aligned(16))) ushort_t Abuf[2][64 * 64];   // 16KB
  __shared__ __attribute__((aligned(16))) ushort_t Bbuf[2][256 * 64];  // 64KB

  const int bid = blockIdx.x;  // 512
  const int rowid = bid & 255;
  const int kh = bid >> 8;
  const int lb = ((rowid & 7) << 5) | (rowid >> 3);  // XCD-contiguous (b,h)
  const int b = lb >> 6;
  const int h = lb & 63;
  const int t = threadIdx.x;
  const int wave = t >> 6;
  const int lane = t & 63;
  const int wq = lane >> 4;
  const int wr = lane & 15;
  const int wm = wave >> 2;
  const int wn = wave & 3;
  const int s_w = t >> 3;
  const int c8 = t & 7;

  const f32x4 zero = {0.f, 0.f, 0.f, 0.f};
  f32x4 acc[2][4];
  #pragma unroll
  for (int i = 0; i < 2; ++i)
    #pragma unroll
    for (int j = 0; j < 4; ++j) acc[i][j] = zero;

  const ushort_t* xtb = xt + (size_t)b * 4096 * 256;
  const float* offb = off + (size_t)b * 18 * 4096 + h * 64 + s_w;

  if (kh == 0)
    run_gemm<0>(offb, xtb, wb, &Abuf[0][0], &Bbuf[0][0], h, s_w, c8, t, wm, wn, wq, wr, acc);
  else
    run_gemm<1>(offb, xtb, wb, &Abuf[0][0], &Bbuf[0][0], h, s_w, c8, t, wm, wn, wq, wr, acc);

  ushort_t* yb = (kh ? y1 : y0) + ((size_t)(b * 4096 + h * 64)) * 256;
  #pragma unroll
  for (int tm = 0; tm < 2; ++tm) {
    #pragma unroll
    for (int tn = 0; tn < 4; ++tn) {
      const int o = wn * 64 + tn * 16 + wr;
      #pragma unroll
      for (int r2 = 0; r2 < 4; ++r2) {
        const int ww = wm * 32 + tm * 16 + wq * 4 + r2;
        yb[ww * 256 + o] = f2bf(acc[tm][tn][r2]);
      }
    }
  }
}

// ---------------- combine partials + GN stats + transpose to [b][o][s] ----------------
// block = (b, st, ot): 64s x 64o tile. Vectorized uint4 reads of y0,y1 (8 bf16),
// f32 add, stats partials (each uint4 spans exactly one 8-wide o-group),
// LDS transpose, write yc[b][o][s] bf16 (apply becomes pure streaming).
__global__ __launch_bounds__(256) void k_comb(const ushort_t* __restrict__ y0,
                                              const ushort_t* __restrict__ y1,
                                              ushort_t* __restrict__ yc,
                                              float* __restrict__ stats) {
  __shared__ float tile[64][65];
  const int bid = blockIdx.x;                    // 1024
  const int lb = ((bid & 7) << 7) | (bid >> 3);  // XCD-contiguous
  const int b = lb >> 8;
  const int st = (lb >> 2) & 63;
  const int ot = lb & 3;
  const int t = threadIdx.x;
  const size_t ybase = ((size_t)(b * 4096 + st * 64)) * 256 + ot * 64;
  float sum = 0.f, ss = 0.f;
  #pragma unroll
  for (int i = 0; i < 2; ++i) {
    const int u = t + 256 * i;
    const int s_l = u >> 3;  // 0..63
    const int o8 = u & 7;    // 8-wide o-subgroup
    const size_t adr = ybase + (size_t)s_l * 256 + o8 * 8;
    const uint4 a = *(const uint4*)(y0 + adr);
    const uint4 c = *(const uint4*)(y1 + adr);
    float v[8];
    v[0] = bflo(a.x) + bflo(c.x); v[1] = bfhi(a.x) + bfhi(c.x);
    v[2] = bflo(a.y) + bflo(c.y); v[3] = bfhi(a.y) + bfhi(c.y);
    v[4] = bflo(a.z) + bflo(c.z); v[5] = bfhi(a.z) + bfhi(c.z);
    v[6] = bflo(a.w) + bflo(c.w); v[7] = bfhi(a.w) + bfhi(c.w);
    #pragma unroll
    for (int j = 0; j < 8; ++j) {
      sum += v[j];
      ss += v[j] * v[j];
      tile[s_l][o8 * 8 + j] = v[j];
    }
  }
  // group of this thread = ot*8 + (t&7); fold lanes differing in bits 3,4,5
  #pragma unroll
  for (int d = 8; d < 64; d <<= 1) {
    sum += __shfl_xor(sum, d, 64);
    ss += __shfl_xor(ss, d, 64);
  }
  if ((t & 63) < 8) {
    const int g = ot * 8 + (t & 7);
    atomicAdd(&stats[(b * 32 + g) * 2], sum);
    atomicAdd(&stats[(b * 32 + g) * 2 + 1], ss);
  }
  __syncthreads();
  // transposed write: 8 s per thread for one o
  #pragma unroll
  for (int i = 0; i < 2; ++i) {
    const int u = t + 256 * i;
    const int o_l = u >> 3;  // 0..63
    const int s8 = u & 7;
    float v[8];
    #pragma unroll
    for (int j = 0; j < 8; ++j) v[j] = tile[s8 * 8 + j][o_l];
    uint4 r;
    r.x = f2bf_bits(v[0]) | (f2bf_bits(v[1]) << 16);
    r.y = f2bf_bits(v[2]) | (f2bf_bits(v[3]) << 16);
    r.z = f2bf_bits(v[4]) | (f2bf_bits(v[5]) << 16);
    r.w = f2bf_bits(v[6]) | (f2bf_bits(v[7]) << 16);
    *(uint4*)(yc + ((size_t)(b * 256 + ot * 64 + o_l)) * 4096 + st * 64 + s8 * 8) = r;
  }
}

// ---------------- GN apply + ReLU: pure streaming over [b][o][s] ----------------
__global__ __launch_bounds__(256) void k_apply(const ushort_t* __restrict__ yc,
                                               const float* __restrict__ stats,
                                               const float* __restrict__ gamma,
                                               const float* __restrict__ beta,
                                               float* __restrict__ out) {
  const int bid = blockIdx.x;                    // 2048
  const int lb = ((bid & 7) << 8) | (bid >> 3);  // XCD-contiguous
  const size_t base = (size_t)lb * 2048 + threadIdx.x * 8;  // element index
  const int b = (int)(base >> 20);
  const int o = (int)((base >> 12) & 255);
  const int g = o >> 3;
  const float s1 = stats[(b * 32 + g) * 2];
  const float s2 = stats[(b * 32 + g) * 2 + 1];
  const float mean = s1 * (1.f / 32768.f);
  const float var = s2 * (1.f / 32768.f) - mean * mean;
  const float rstd = rsqrtf(var + 1e-5f);
  const float sc = rstd * gamma[o];
  const float sh = beta[o] - mean * sc;
  const uint4 a = *(const uint4*)(yc + base);
  float v[8];
  v[0] = bflo(a.x); v[1] = bfhi(a.x);
  v[2] = bflo(a.y); v[3] = bfhi(a.y);
  v[4] = bflo(a.z); v[5] = bfhi(a.z);
  v[6] = bflo(a.w); v[7] = bfhi(a.w);
  float4 f0, f1;
  f0.x = fmaxf(v[0] * sc + sh, 0.f);
  f0.y = fmaxf(v[1] * sc + sh, 0.f);
  f0.z = fmaxf(v[2] * sc + sh, 0.f);
  f0.w = fmaxf(v[3] * sc + sh, 0.f);
  f1.x = fmaxf(v[4] * sc + sh, 0.f);
  f1.y = fmaxf(v[5] * sc + sh, 0.f);
  f1.z = fmaxf(v[6] * sc + sh, 0.f);
  f1.w = fmaxf(v[7] * sc + sh, 0.f);
  *(float4*)(out + base) = f0;
  *(float4*)(out + base + 4) = f1;
}

extern "C" void kernel_launch(void* const* d_in, const int* in_sizes, int n_in,
                              void* d_out, int out_size, void* d_ws, size_t ws_size,
                              hipStream_t stream) {
  const float* x = (const float*)d_in[0];       // (4,256,64,64)
  const float* off = (const float*)d_in[1];     // (4,18,64,64)
  const float* w = (const float*)d_in[2];       // (256,256,3,3)
  const float* gamma = (const float*)d_in[3];   // (256)
  const float* beta = (const float*)d_in[4];    // (256)
  float* out = (float*)d_out;

  char* ws = (char*)d_ws;
  ushort_t* y0 = (ushort_t*)(ws);                 //  8,388,608 B  partial kh=0, bf16
  ushort_t* y1 = (ushort_t*)(ws + 8388608);       //  8,388,608 B  partial kh=1, bf16
  ushort_t* xt = (ushort_t*)(ws + 16777216);      //  8,388,608 B  [b][h][w][c] bf16
  ushort_t* yc = xt;                              //  reuses xt region after gemm
  ushort_t* wb = (ushort_t*)(ws + 25165824);      //  1,179,648 B  [k][o][c] bf16
  float* stats = (float*)(ws + 26345472);         //      1,024 B  [b][g]{sum,ss}

  k_prep<<<1280, 256, 0, stream>>>(x, w, xt, wb, stats);
  k_gemm<<<512, 512, 0, stream>>>(off, xt, wb, y0, y1);
  k_comb<<<1024, 256, 0, stream>>>(y0, y1, yc, stats);
  k_apply<<<2048, 256, 0, stream>>>(yc, stats, gamma, beta, out);
}